// Round 11
// baseline (651.476 us; speedup 1.0000x reference)
//
#include <hip/hip_runtime.h>

#define N_NODES 50000
#define N_EDGES 800000
#define NODE_IN 256
#define EDGE_IN 64
#define HID 128
#define OUTD 16
#define LN_EPS 1e-5f
// padded edge-array capacity: every segment padded to multiple of 4
#define CAPE (((N_EDGES + 3 * N_NODES) + 63) & ~63)   // 950016, 64-aligned

typedef __attribute__((ext_vector_type(4))) float f32x4;
typedef __attribute__((ext_vector_type(8))) _Float16 half8;
typedef __attribute__((ext_vector_type(4))) _Float16 half4;

__device__ __forceinline__ float gelu_exact(float x) {
    return 0.5f * x * (1.0f + erff(x * 0.70710678118654752f));
}

// ---------------------------------------------------------------------------
// Zero helper (kernel, capture-safe).
// ---------------------------------------------------------------------------
__global__ __launch_bounds__(256) void zero_kernel(int4* __restrict__ p, int n4) {
    int i = blockIdx.x * 256 + threadIdx.x;
    const int stride = gridDim.x * 256;
    for (; i < n4; i += stride) p[i] = make_int4(0, 0, 0, 0);
}

// ---------------------------------------------------------------------------
// Setup: transpose weights to [col][k] fp16 (MFMA B fragments become 16B loads)
// ---------------------------------------------------------------------------
__global__ void setup_kernel(const float* __restrict__ Wn, const float* __restrict__ We,
                             _Float16* __restrict__ WTn, _Float16* __restrict__ WTe) {
    int t = blockIdx.x * blockDim.x + threadIdx.x;
    int stride = gridDim.x * blockDim.x;
    for (int i = t; i < HID * NODE_IN; i += stride) {
        int n = i >> 8, k = i & 255;
        WTn[i] = (_Float16)Wn[k * HID + n];
    }
    for (int i = t; i < HID * EDGE_IN; i += stride) {
        int n = i >> 6, k = i & 63;
        WTe[i] = (_Float16)We[k * HID + n];
    }
}

// ---------------------------------------------------------------------------
// Grouping (NOT a stable sort -- downstream accumulation is exact int64
// fixed-point, hence commutative: any within-segment order yields bit-
// identical h64).  Segments are PADDED to multiples of 4 so that every
// 4-row thread window in fagg lies in exactly one segment.
// ---------------------------------------------------------------------------
__global__ __launch_bounds__(256) void count_kernel(const int* __restrict__ dst,
                                                    int* __restrict__ tot) {
    int e = blockIdx.x * 256 + threadIdx.x;
    if (e < N_EDGES) atomicAdd(&tot[dst[e]], 1);
}

// scans PADDED counts: pt[d] = (tot[d]+3) & ~3
__global__ __launch_bounds__(256) void scan1_kernel(const int* __restrict__ tot,
                                                    int* __restrict__ offs,
                                                    int* __restrict__ btot) {
    __shared__ int lsum[256];
    const int t = threadIdx.x;
    const int base = blockIdx.x * 1024 + t * 4;
    int v[4]; int s = 0;
    #pragma unroll
    for (int j = 0; j < 4; ++j) {
        int idx = base + j;
        v[j] = (idx < N_NODES) ? ((tot[idx] + 3) & ~3) : 0;
        s += v[j];
    }
    lsum[t] = s;
    __syncthreads();
    for (int d = 1; d < 256; d <<= 1) {
        int x = (t >= d) ? lsum[t - d] : 0;
        __syncthreads();
        lsum[t] += x;
        __syncthreads();
    }
    int excl = lsum[t] - s;
    if (t == 255) btot[blockIdx.x] = lsum[255];
    int run = excl;
    #pragma unroll
    for (int j = 0; j < 4; ++j) {
        int idx = base + j;
        if (idx < N_NODES) offs[idx] = run;
        run += v[j];
    }
}

// adds block prefix; initializes placement cursors; writes offs[N_NODES]=EPAD
__global__ __launch_bounds__(256) void scan2_kernel(int* __restrict__ offs,
                                                    const int* __restrict__ btot,
                                                    int* __restrict__ cur) {
    int s = 0;
    for (int i = 0; i < (int)blockIdx.x; ++i) s += btot[i];
    const int t = threadIdx.x;
    const int base = blockIdx.x * 1024 + t * 4;
    #pragma unroll
    for (int j = 0; j < 4; ++j) {
        int idx = base + j;
        if (idx < N_NODES) {
            int v = offs[idx] + s;
            offs[idx] = v;
            cur[idx] = v;
        }
    }
    if (blockIdx.x == gridDim.x - 1 && t == 0)
        offs[N_NODES] = s + btot[blockIdx.x];      // EPAD (multiple of 4)
}

// prefill padded arrays: perm=0 (valid row for harmless loads), psrc=-1
// (pad flag -> product forced to 0), pdst=-1 (tail sentinel, never closed).
__global__ __launch_bounds__(256) void prefill_kernel(int* __restrict__ perm,
                                                      int* __restrict__ psrc,
                                                      int* __restrict__ pdst) {
    int i = blockIdx.x * 256 + threadIdx.x;
    if (i < CAPE) { perm[i] = 0; psrc[i] = -1; pdst[i] = -1; }
}

// in-span pads [offs[n]+tot[n], offs[n+1]) get pdst=n so they extend the
// segment (psrc stays -1 -> contribute exact zero).
__global__ __launch_bounds__(256) void padfill_kernel(const int* __restrict__ tot,
                                                      const int* __restrict__ offs,
                                                      int* __restrict__ pdst) {
    int n = blockIdx.x * 256 + threadIdx.x;
    if (n < N_NODES) {
        int s = offs[n] + tot[n], e = offs[n + 1];
        for (int p = s; p < e; ++p) pdst[p] = n;
    }
}

// E-parallel grouping placement (racy order within segment; harmless).
__global__ __launch_bounds__(256) void place2_kernel(const int* __restrict__ src,
                                                     const int* __restrict__ dst,
                                                     int* __restrict__ cur,
                                                     int* __restrict__ perm,
                                                     int* __restrict__ psrc,
                                                     int* __restrict__ pdst) {
    int e = blockIdx.x * 256 + threadIdx.x;
    if (e < N_EDGES) {
        const int d = dst[e];
        const int pos = atomicAdd(&cur[d], 1);
        perm[pos] = e;
        psrc[pos] = src[e];
        pdst[pos] = d;
    }
}

// ---------------------------------------------------------------------------
// Node projection: hv = LN(GELU(X @ Wn)), stored fp16 PERMUTED:
// hv[row*128 + x*8 + c] = value at col (16c + x).
// ---------------------------------------------------------------------------
__global__ __launch_bounds__(256) void node_kernel(
    const float* __restrict__ X,
    const _Float16* __restrict__ WT,    // [HID][NODE_IN]
    const float* __restrict__ g, const float* __restrict__ b,
    _Float16* __restrict__ hv)
{
    __shared__ __align__(16) _Float16 lA[64 * 72];
    __shared__ __align__(16) _Float16 lB[128 * 72];

    const int t = threadIdx.x;
    const int wave = t >> 6, lane = t & 63;
    const int x15 = lane & 15, quad = lane >> 4;
    const int row0 = blockIdx.x * 64;

    float gc[8], bc[8];
    #pragma unroll
    for (int c = 0; c < 8; ++c) { gc[c] = g[16 * c + x15]; bc[c] = b[16 * c + x15]; }

    f32x4 acc[8];
    #pragma unroll
    for (int c = 0; c < 8; ++c) acc[c] = (f32x4)(0.0f);

    for (int kc = 0; kc < 4; ++kc) {
        const int k0 = kc * 64;
        __syncthreads();
        #pragma unroll
        for (int j = 0; j < 4; ++j) {
            int idx = j * 1024 + t * 4;
            int r = idx >> 6, kk = idx & 63;
            int grow = row0 + r;
            float4 v = make_float4(0.f, 0.f, 0.f, 0.f);
            if (grow < N_NODES) v = *(const float4*)(X + grow * NODE_IN + k0 + kk);
            half4 h4;
            h4[0] = (_Float16)v.x; h4[1] = (_Float16)v.y;
            h4[2] = (_Float16)v.z; h4[3] = (_Float16)v.w;
            *(half4*)(lA + r * 72 + kk) = h4;
        }
        #pragma unroll
        for (int j = 0; j < 4; ++j) {
            int idx = j * 2048 + t * 8;
            int n = idx >> 6, kk = idx & 63;
            half8 v = *(const half8*)(WT + n * NODE_IN + k0 + kk);
            *(half8*)(lB + n * 72 + kk) = v;
        }
        __syncthreads();
        #pragma unroll
        for (int ks = 0; ks < 2; ++ks) {
            half8 a = *(const half8*)(lA + (wave * 16 + x15) * 72 + ks * 32 + quad * 8);
            #pragma unroll
            for (int c = 0; c < 8; ++c) {
                half8 bb = *(const half8*)(lB + (c * 16 + x15) * 72 + ks * 32 + quad * 8);
                acc[c] = __builtin_amdgcn_mfma_f32_16x16x32_f16(a, bb, acc[c], 0, 0, 0);
            }
        }
    }

    float v[8][4], s[4], sq[4];
    #pragma unroll
    for (int r = 0; r < 4; ++r) { s[r] = 0.f; sq[r] = 0.f; }
    #pragma unroll
    for (int c = 0; c < 8; ++c)
        #pragma unroll
        for (int r = 0; r < 4; ++r) {
            float x = gelu_exact(acc[c][r]);
            v[c][r] = x; s[r] += x; sq[r] += x * x;
        }
    #pragma unroll
    for (int m = 1; m <= 8; m <<= 1)
        #pragma unroll
        for (int r = 0; r < 4; ++r) {
            s[r]  += __shfl_xor(s[r],  m, 64);
            sq[r] += __shfl_xor(sq[r], m, 64);
        }
    #pragma unroll
    for (int r = 0; r < 4; ++r) {
        int row = row0 + wave * 16 + quad * 4 + r;
        if (row >= N_NODES) continue;
        float mean = s[r] * (1.f / 128.f);
        float var  = sq[r] * (1.f / 128.f) - mean * mean;
        float rstd = rsqrtf(var + LN_EPS);
        half8 o;
        #pragma unroll
        for (int c = 0; c < 8; ++c)
            o[c] = (_Float16)((v[c][r] - mean) * rstd * gc[c] + bc[c]);
        *(half8*)(hv + row * HID + x15 * 8) = o;
    }
}

// ---------------------------------------------------------------------------
// Fused grouped aggregation, padded-segment edition.
// Segments padded to multiples of 4 -> every thread's 4 consecutive rows lie
// in ONE segment: no run splitting, no LDS atomics.  Thread accumulates its
// int64 partial (8 cols) in registers, plain-stores to lpart[16][128]; a
// 128-thread walk over the 16 rowgroups does the deterministic segmented sum
// (block-owned -> plain store, spanning -> int64 global atomicAdd, ~2/block).
// Pad rows have psrc=-1 -> contribute exact 0.  Bit-deterministic.
// ---------------------------------------------------------------------------
__global__ __launch_bounds__(256) void fagg_kernel(
    const float* __restrict__ EF,
    const int* __restrict__ perm, const int* __restrict__ psrc,
    const int* __restrict__ pdst, const int* __restrict__ offs,
    const _Float16* __restrict__ WT,
    const float* __restrict__ g, const float* __restrict__ b,
    const _Float16* __restrict__ hv,
    long long* __restrict__ h64)
{
    __shared__ __align__(16) _Float16 lA[64 * 72];            // 9.2 KB
    __shared__ long long lpart[16 * 128];                     // 16 KB
    __shared__ int lperm[64];
    __shared__ int lsrc[64];
    __shared__ int ldst[64];

    const int base = blockIdx.x * 64;               // padded-position base
    if (base >= offs[N_NODES]) return;              // tail blocks: uniform exit

    const int t = threadIdx.x;
    const int wave = t >> 6, lane = t & 63;
    const int x15 = lane & 15, quad = lane >> 4;

    half8 Bf[8][2];
    #pragma unroll
    for (int c = 0; c < 8; ++c)
        #pragma unroll
        for (int ks = 0; ks < 2; ++ks)
            Bf[c][ks] = *(const half8*)(WT + (c * 16 + x15) * EDGE_IN + ks * 32 + quad * 8);

    float gc[8], bc[8];
    #pragma unroll
    for (int c = 0; c < 8; ++c) { gc[c] = g[16 * c + x15]; bc[c] = b[16 * c + x15]; }

    if (t < 64)       lperm[t]      = perm[base + t];
    else if (t < 128) lsrc[t - 64]  = psrc[base + t - 64];
    else if (t < 192) ldst[t - 128] = pdst[base + t - 128];
    __syncthreads();

    // stage 64 gathered EF rows (256B each) fp32 -> fp16
    #pragma unroll
    for (int j = 0; j < 4; ++j) {
        int idx = j * 1024 + t * 4;
        int r = idx >> 6, kk = idx & 63;
        const float4 v = *(const float4*)(EF + (size_t)lperm[r] * EDGE_IN + kk);
        half4 h4;
        h4[0] = (_Float16)v.x; h4[1] = (_Float16)v.y;
        h4[2] = (_Float16)v.z; h4[3] = (_Float16)v.w;
        *(half4*)(lA + r * 72 + kk) = h4;
    }
    __syncthreads();

    // MFMA edge projection
    f32x4 acc[8];
    #pragma unroll
    for (int c = 0; c < 8; ++c) acc[c] = (f32x4)(0.0f);
    #pragma unroll
    for (int ks = 0; ks < 2; ++ks) {
        half8 a = *(const half8*)(lA + (wave * 16 + x15) * 72 + ks * 32 + quad * 8);
        #pragma unroll
        for (int c = 0; c < 8; ++c)
            acc[c] = __builtin_amdgcn_mfma_f32_16x16x32_f16(a, Bf[c][ks], acc[c], 0, 0, 0);
    }

    // LN stats per row
    float s[4], sq[4];
    #pragma unroll
    for (int r = 0; r < 4; ++r) { s[r] = 0.f; sq[r] = 0.f; }
    #pragma unroll
    for (int c = 0; c < 8; ++c)
        #pragma unroll
        for (int r = 0; r < 4; ++r) { float x = acc[c][r]; s[r] += x; sq[r] += x * x; }
    #pragma unroll
    for (int m = 1; m <= 8; m <<= 1)
        #pragma unroll
        for (int r = 0; r < 4; ++r) {
            s[r]  += __shfl_xor(s[r],  m, 64);
            sq[r] += __shfl_xor(sq[r], m, 64);
        }

    // per-thread int64 partial over its 4 same-segment rows
    const int rg = wave * 4 + quad;                 // rowgroup 0..15
    long long a8[8];
    #pragma unroll
    for (int c = 0; c < 8; ++c) a8[c] = 0;

    #pragma unroll
    for (int rr = 0; rr < 4; ++rr) {
        const int erow = rg * 4 + rr;
        const int se = lsrc[erow];
        if (se >= 0) {
            const half8 hg = *(const half8*)(hv + (size_t)se * HID + x15 * 8);
            const float mean = s[rr] * (1.f / 128.f);
            const float var  = sq[rr] * (1.f / 128.f) - mean * mean;
            const float rstd = rsqrtf(var + LN_EPS);
            #pragma unroll
            for (int c = 0; c < 8; ++c) {
                const float he = __expf((acc[c][rr] - mean) * rstd * gc[c] + bc[c]);
                a8[c] += llrintf(he * (float)hg[c] * 4294967296.0f);  // 2^32 fixed
            }
        }
    }
    long long* lp = &lpart[rg * 128 + x15 * 8];
    #pragma unroll
    for (int c = 0; c < 8; ++c) lp[c] = a8[c];
    __syncthreads();

    // deterministic segmented walk over 16 rowgroups (128 threads, col each)
    if (t < 128) {
        const int j = t;
        long long run = 0;
        int rs = 0;                                 // first rowgroup of run
        for (int rgw = 0; rgw < 16; ++rgw) {
            run += lpart[rgw * 128 + j];
            const int d = ldst[rgw * 4];
            const bool close = (rgw == 15) || (ldst[rgw * 4 + 4] != d);
            if (close) {
                if (d >= 0) {
                    long long* hp = h64 + (size_t)d * HID + j;
                    if (offs[d] == base + rs * 4 && offs[d + 1] == base + rgw * 4 + 4)
                        *hp = run;                  // sole owner of segment
                    else
                        atomicAdd((unsigned long long*)hp, (unsigned long long)run);
                }
                run = 0; rs = rgw + 1;
            }
        }
    }
}

// ---------------------------------------------------------------------------
// Out projection: out = LN(GELU(h @ Wout)).  h arrives as int64 fixed-point
// (scale 2^32) in permuted layout; un-permute + convert in LDS staging.
// ---------------------------------------------------------------------------
__global__ __launch_bounds__(256) void out_kernel(
    const long long* __restrict__ h64,
    const float* __restrict__ W,       // [128][16]
    const float* __restrict__ g, const float* __restrict__ b,
    float* __restrict__ out)
{
    __shared__ float lW[HID * OUTD];
    __shared__ float lh[16][HID];
    const int t = threadIdx.x;
    const int node0 = blockIdx.x * 16;

    for (int i = t; i < HID * OUTD; i += 256) lW[i] = W[i];
    for (int i = t; i < 16 * HID; i += 256) {
        int row = i >> 7, p = i & 127;
        int k = 16 * (p & 7) + (p >> 3);     // un-permute: p = x*8 + c -> k = 16c + x
        int grow = node0 + row;
        lh[row][k] = (grow < N_NODES)
                   ? (float)h64[(size_t)grow * HID + p] * 0x1p-32f
                   : 0.f;
    }
    __syncthreads();

    const int i = t >> 4, j = t & 15;
    float acc = 0.f;
    #pragma unroll 8
    for (int k = 0; k < HID; ++k)
        acc = fmaf(lh[i][k], lW[k * OUTD + j], acc);
    float x = gelu_exact(acc);
    float s = x, sq = x * x;
    #pragma unroll
    for (int m = 1; m <= 8; m <<= 1) {
        s  += __shfl_xor(s,  m, 64);
        sq += __shfl_xor(sq, m, 64);
    }
    float mean = s * (1.f / 16.f);
    float var  = sq * (1.f / 16.f) - mean * mean;
    float rstd = rsqrtf(var + LN_EPS);
    int grow = node0 + i;
    if (grow < N_NODES) out[grow * OUTD + j] = (x - mean) * rstd * g[j] + b[j];
}

// ---------------------------------------------------------------------------
// Single unconditional path; no ws_size-dependent behavior (tripwire lesson).
// ---------------------------------------------------------------------------
extern "C" void kernel_launch(void* const* d_in, const int* in_sizes, int n_in,
                              void* d_out, int out_size, void* d_ws, size_t ws_size,
                              hipStream_t stream) {
    const float* node_feats = (const float*)d_in[0];
    const float* edge_feats = (const float*)d_in[1];
    const int*   src        = (const int*)d_in[2];
    const int*   dst        = (const int*)d_in[3];
    const float* W_node     = (const float*)d_in[4];
    const float* g_node     = (const float*)d_in[5];
    const float* b_node     = (const float*)d_in[6];
    const float* W_edge     = (const float*)d_in[7];
    const float* g_edge     = (const float*)d_in[8];
    const float* b_edge     = (const float*)d_in[9];
    const float* W_out      = (const float*)d_in[10];
    const float* g_out      = (const float*)d_in[11];
    const float* b_out      = (const float*)d_in[12];
    float* out = (float*)d_out;

    char* ws = (char*)d_ws;
    size_t o = 0;
    _Float16* hv  = (_Float16*)(ws + o); o += (size_t)N_NODES * HID * 2;        // 12.8 MB
    _Float16* WTn = (_Float16*)(ws + o); o += (size_t)HID * NODE_IN * 2;        // 64 KB
    _Float16* WTe = (_Float16*)(ws + o); o += (size_t)HID * EDGE_IN * 2;        // 16 KB
    int* tot  = (int*)(ws + o); o += (size_t)N_NODES * 4;                       // 200 KB
    int* offs = (int*)(ws + o); o += (size_t)(N_NODES + 16) * 4;                // 200 KB
    int* btot = (int*)(ws + o); o += 1024;
    int* cur  = (int*)(ws + o); o += (size_t)N_NODES * 4;                       // 200 KB
    int* perm = (int*)(ws + o); o += (size_t)CAPE * 4;                          // 3.8 MB
    int* psrc = (int*)(ws + o); o += (size_t)CAPE * 4;                          // 3.8 MB
    int* pdst = (int*)(ws + o); o += (size_t)CAPE * 4;                          // 3.8 MB
    o = (o + 511) & ~(size_t)511;
    long long* h64 = (long long*)(ws + o);                                      // 51.2 MB

    zero_kernel<<<49, 256, 0, stream>>>((int4*)tot, N_NODES / 4);
    setup_kernel<<<128, 256, 0, stream>>>(W_node, W_edge, WTn, WTe);
    node_kernel<<<(N_NODES + 63) / 64, 256, 0, stream>>>(node_feats, WTn, g_node, b_node, hv);
    count_kernel<<<N_EDGES / 256, 256, 0, stream>>>(dst, tot);
    scan1_kernel<<<49, 256, 0, stream>>>(tot, offs, btot);
    scan2_kernel<<<49, 256, 0, stream>>>(offs, btot, cur);
    prefill_kernel<<<(CAPE + 255) / 256, 256, 0, stream>>>(perm, psrc, pdst);
    padfill_kernel<<<(N_NODES + 255) / 256, 256, 0, stream>>>(tot, offs, pdst);
    place2_kernel<<<N_EDGES / 256, 256, 0, stream>>>(src, dst, cur, perm, psrc, pdst);
    zero_kernel<<<2048, 256, 0, stream>>>((int4*)h64, (int)((size_t)N_NODES * HID * 8 / 16));
    fagg_kernel<<<CAPE / 64, 256, 0, stream>>>(edge_feats, perm, psrc, pdst, offs,
                                               WTe, g_edge, b_edge, hv, h64);
    out_kernel<<<(N_NODES + 15) / 16, 256, 0, stream>>>(h64, W_out, g_out, b_out, out);
}